// Round 3
// baseline (419.867 us; speedup 1.0000x reference)
//
#include <hip/hip_runtime.h>
#include <hip/hip_bf16.h>
#include <stdint.h>

#define BATCH 8
#define SEQ   4096
#define EMB   1024
#define HD    128

typedef __attribute__((ext_vector_type(8))) short short8;
typedef __attribute__((ext_vector_type(4))) float f32x4;

__device__ inline unsigned short f2bf(float f) {
    union { float f; unsigned int u; } c; c.f = f;
    unsigned int u = c.u;
    unsigned int r = (u + 0x7fffu + ((u >> 16) & 1u)) >> 16;
    return (unsigned short)r;
}

#define GLDS16(gp, lp) __builtin_amdgcn_global_load_lds( \
    (const __attribute__((address_space(1))) void*)(gp), \
    (__attribute__((address_space(3))) void*)(lp), 16, 0, 0)

// ---------------------------------------------------------------------------
// prep: transpose-pack Wq|Wk|Wv -> bf16 wt[384][1024] via LDS (coalesced both
// sides). Grid: 24 blocks = 3 sel x 8 k-tiles of 128.
// ---------------------------------------------------------------------------
__global__ __launch_bounds__(256) void prep_kernel(
    const float* __restrict__ Wq, const float* __restrict__ bq,
    const float* __restrict__ Wk, const float* __restrict__ bk,
    const float* __restrict__ Wv, const float* __restrict__ bv,
    unsigned short* __restrict__ wt, float* __restrict__ biasc)
{
    const int sel = blockIdx.x >> 3;
    const int kk0 = (blockIdx.x & 7) * 128;
    const int tid = threadIdx.x;
    const float* W = (sel == 0) ? Wq : (sel == 1) ? Wk : Wv;
    __shared__ unsigned short T[128][136];
    for (int r = 0; r < 128; r += 2) {
        int row = r + (tid >> 7);
        int h   = tid & 127;
        T[row][h] = f2bf(W[(size_t)(kk0 + row) * HD + h]);
    }
    __syncthreads();
    const int h = tid >> 1, kb0 = (tid & 1) * 64;
    unsigned short* dst = wt + (size_t)(sel * 128 + h) * EMB + kk0 + kb0;
    for (int kk = 0; kk < 64; kk += 8) {
        union { unsigned short us[8]; uint4 v; } pk;
#pragma unroll
        for (int u = 0; u < 8; ++u) pk.us[u] = T[kb0 + kk + u][h];
        *(uint4*)(dst + kk) = pk.v;
    }
    if ((blockIdx.x & 7) == 0 && tid < 128) {
        const float* bp = (sel == 0) ? bq : (sel == 1) ? bk : bv;
        biasc[sel * 128 + tid] = bp[tid];
    }
}

// ---------------------------------------------------------------------------
// gemm_qkv: fused QKV projection. 512 blocks x 64 rows, 4 waves, wave tile
// 96 wcols x 64 xrows. Double-buffered LDS, swizzled Bs, MFMA(A=W, B=x) so
// D rows = w-cols -> packed 8B q/k stores. q pre-scaled by 1/sqrt(128)*log2e.
// ---------------------------------------------------------------------------
__global__ __launch_bounds__(256, 2) void gemm_qkv(
    const float* __restrict__ x, const unsigned short* __restrict__ wt,
    const float* __restrict__ biasc,
    unsigned short* __restrict__ q, unsigned short* __restrict__ kOut,
    unsigned short* __restrict__ vt)
{
    const int m0  = blockIdx.x * 64;
    const int tid = threadIdx.x;
    const int wave = tid >> 6, lane = tid & 63;
    const int quad = lane >> 4, l15 = lane & 15;

    __shared__ unsigned short As[2][64][40];     // x tile, +8 pad (80B rows, 16B-aligned)
    __shared__ unsigned short Bs[2][12288];      // W tile [384][32], chunk-swizzled

    f32x4 acc[6][4];                              // [w-frag][x-frag]
#pragma unroll
    for (int i = 0; i < 6; ++i)
#pragma unroll
        for (int j = 0; j < 4; ++j)
            acc[i][j] = (f32x4){0.f, 0.f, 0.f, 0.f};

    const int clog = (lane & 3) ^ ((lane >> 2) & 3);   // swizzled logical chunk
    float4 aR[2];

#define LOAD_A(kt)                                                         \
    {                                                                      \
        _Pragma("unroll")                                                  \
        for (int i = 0; i < 2; ++i) {                                      \
            int e = tid + i * 256, row = e >> 3, kc = (e & 7) * 4;         \
            aR[i] = *(const float4*)(x + (size_t)(m0 + row) * EMB + (kt) * 32 + kc); \
        }                                                                  \
    }
#define WRITE_A(buf)                                                       \
    {                                                                      \
        _Pragma("unroll")                                                  \
        for (int i = 0; i < 2; ++i) {                                      \
            int e = tid + i * 256, row = e >> 3, kc = (e & 7) * 4;         \
            union { unsigned short us[4]; uint2 v; } pk;                   \
            pk.us[0] = f2bf(aR[i].x); pk.us[1] = f2bf(aR[i].y);            \
            pk.us[2] = f2bf(aR[i].z); pk.us[3] = f2bf(aR[i].w);            \
            *(uint2*)&As[buf][row][kc] = pk.v;                             \
        }                                                                  \
    }
#define STAGE_B(kt, buf)                                                   \
    {                                                                      \
        _Pragma("unroll")                                                  \
        for (int i = 0; i < 6; ++i) {                                      \
            int cid = i * 4 + wave;                                        \
            int n = cid * 16 + (lane >> 2);                                \
            const unsigned short* gp = wt + (size_t)n * EMB + (kt) * 32 + clog * 8; \
            GLDS16(gp, &Bs[buf][cid * 512]);                               \
        }                                                                  \
    }

    LOAD_A(0);
    STAGE_B(0, 0);
    WRITE_A(0);
    int cur = 0;

    for (int kt = 0; kt < 32; ++kt) {
        __syncthreads();
        if (kt < 31) { STAGE_B(kt + 1, cur ^ 1); LOAD_A(kt + 1); }
        short8 af[4], bfr[6];
#pragma unroll
        for (int mj = 0; mj < 4; ++mj)
            af[mj] = *(const short8*)&As[cur][mj * 16 + l15][quad * 8];
#pragma unroll
        for (int ni = 0; ni < 6; ++ni) {
            int row = wave * 96 + ni * 16 + l15;
            bfr[ni] = *(const short8*)&Bs[cur][row * 32 + (quad ^ (l15 & 3)) * 8];
        }
#pragma unroll
        for (int ni = 0; ni < 6; ++ni)
#pragma unroll
            for (int mj = 0; mj < 4; ++mj)
                acc[ni][mj] = __builtin_amdgcn_mfma_f32_16x16x32_bf16(
                    bfr[ni], af[mj], acc[ni][mj], 0, 0, 0);
        if (kt < 31) WRITE_A(cur ^ 1);
        cur ^= 1;
    }

    // ---- epilogue: D[m=wcol][n=xrow]; lane holds 4 consecutive wcols ----
    const float qscale = 0.08838834764831845f * 1.4426950408889634f;
    const int bb = m0 >> 12;
    const int t0 = m0 & 4095;
#pragma unroll
    for (int ni = 0; ni < 6; ++ni) {
        int colbase = wave * 96 + ni * 16;
        int sel = colbase >> 7;
        int c0 = colbase + quad * 4;             // first of 4 consecutive cols
        float4 bv4 = *(const float4*)&biasc[c0];
#pragma unroll
        for (int mj = 0; mj < 4; ++mj) {
            int m = m0 + mj * 16 + l15;
            if (sel == 0) {
                union { unsigned short us[4]; uint2 v; } pk;
#pragma unroll
                for (int j = 0; j < 4; ++j)
                    pk.us[j] = f2bf((acc[ni][mj][j] + ((const float*)&bv4)[j]) * qscale);
                *(uint2*)&q[(size_t)m * HD + (c0 & 127)] = pk.v;
            } else if (sel == 1) {
                union { unsigned short us[4]; uint2 v; } pk;
#pragma unroll
                for (int j = 0; j < 4; ++j)
                    pk.us[j] = f2bf(acc[ni][mj][j] + ((const float*)&bv4)[j]);
                *(uint2*)&kOut[(size_t)m * HD + (c0 & 127)] = pk.v;
            } else {
#pragma unroll
                for (int j = 0; j < 4; ++j) {
                    int h = (c0 & 127) + j;
                    vt[((size_t)(bb * 128 + h)) * SEQ + t0 + mj * 16 + l15] =
                        f2bf(acc[ni][mj][j] + ((const float*)&bv4)[j]);
                }
            }
        }
    }
#undef LOAD_A
#undef WRITE_A
#undef STAGE_B
}

// ---------------------------------------------------------------------------
// attn: flash attention. 256 blocks = 32 q-tiles(128 rows) x 8 batches, LPT.
// 4 waves x 32 q-rows (Q resident in regs, reused 2x per K/V fragment).
// BN=64 keys/iter; K double-buffered, V staged per-iter; chunk-XOR swizzle
// makes all b128 LDS reads ~2-way (free). LDS = exactly 64 KB.
// ---------------------------------------------------------------------------
__global__ __launch_bounds__(256, 1) void attn_kernel(
    const unsigned short* __restrict__ q, const unsigned short* __restrict__ k,
    const unsigned short* __restrict__ vt, float* __restrict__ out)
{
    const int rank = blockIdx.x;              // 0..255
    const int qt   = 31 - (rank >> 3);        // heavy tiles first (LPT)
    const int b    = rank & 7;
    const int tid  = threadIdx.x;
    const int wave = tid >> 6, lane = tid & 63;
    const int quad = lane >> 4, l15 = lane & 15;

    __shared__ unsigned short Ks[2][8192];    // [kh][key][32] swizzled, 2x16KB
    __shared__ unsigned short Vs[8192];       // [sk][h][32]   swizzled, 16KB
    __shared__ unsigned short P[4 * 2048];    // per-wave [32][64] chunk-swizzled, 16KB

    const int qm0 = qt * 128 + wave * 32;
    const size_t qbase = (size_t)b * SEQ;
    const size_t vbase = (size_t)b * HD * SEQ;
    const int clog = (lane & 3) ^ ((lane >> 2) & 3);

    // stage K tile (16 KB): 4 load_lds per wave
#define STAGE_K(key0, buf)                                                  \
    {                                                                       \
        _Pragma("unroll")                                                   \
        for (int i = 0; i < 4; ++i) {                                       \
            int cid = i * 4 + wave;                                         \
            int kh = cid >> 2, kr = (cid & 3) * 16 + (lane >> 2);           \
            const unsigned short* gp =                                      \
                k + (qbase + (key0) + kr) * HD + kh * 32 + clog * 8;        \
            GLDS16(gp, &Ks[buf][cid * 512]);                                \
        }                                                                   \
    }
#define STAGE_V(key0)                                                       \
    {                                                                       \
        _Pragma("unroll")                                                   \
        for (int i = 0; i < 4; ++i) {                                       \
            int cid = i * 4 + wave;                                         \
            int sk = cid >> 3, h = (cid & 7) * 16 + (lane >> 2);            \
            const unsigned short* gp =                                      \
                vt + vbase + (size_t)h * SEQ + (key0) + sk * 32 + clog * 8; \
            GLDS16(gp, &Vs[cid * 512]);                                     \
        }                                                                   \
    }

    // Q fragments resident (A-layout), 2 m-frags x 4 kh
    short8 qf[2][4];
#pragma unroll
    for (int mi = 0; mi < 2; ++mi)
#pragma unroll
        for (int kh = 0; kh < 4; ++kh)
            qf[mi][kh] = *(const short8*)(q + (qbase + qm0 + mi * 16 + l15) * HD + kh * 32 + quad * 8);

    f32x4 o[2][8];
#pragma unroll
    for (int mi = 0; mi < 2; ++mi)
#pragma unroll
        for (int hi = 0; hi < 8; ++hi) o[mi][hi] = (f32x4){0.f, 0.f, 0.f, 0.f};
    f32x4 m_r[2], l_r[2];
#pragma unroll
    for (int mi = 0; mi < 2; ++mi) {
        m_r[mi] = (f32x4){-1e30f, -1e30f, -1e30f, -1e30f};
        l_r[mi] = (f32x4){0.f, 0.f, 0.f, 0.f};
    }

    const int nkt = 2 * qt + 2;
    STAGE_K(0, 0);
    int cur = 0;

    for (int kt = 0; kt < nkt; ++kt) {
        const int key0 = kt * 64;
        __syncthreads();                       // (a) K[cur] landed; prev PV reads retired
        STAGE_V(key0);
        if (kt + 1 < nkt) STAGE_K((kt + 1) * 64, cur ^ 1);

        // ---- S = Q K^T ----
        f32x4 s[2][4];
#pragma unroll
        for (int mi = 0; mi < 2; ++mi)
#pragma unroll
            for (int ni = 0; ni < 4; ++ni) s[mi][ni] = (f32x4){0.f, 0.f, 0.f, 0.f};
#pragma unroll
        for (int kh = 0; kh < 4; ++kh) {
#pragma unroll
            for (int ni = 0; ni < 4; ++ni) {
                int row = ni * 16 + l15;
                short8 bfr = *(const short8*)&Ks[cur][kh * 2048 + row * 32 + (quad ^ (l15 & 3)) * 8];
                s[0][ni] = __builtin_amdgcn_mfma_f32_16x16x32_bf16(qf[0][kh], bfr, s[0][ni], 0, 0, 0);
                s[1][ni] = __builtin_amdgcn_mfma_f32_16x16x32_bf16(qf[1][kh], bfr, s[1][ni], 0, 0, 0);
            }
        }
        // ---- causal mask (only tiles that touch the diagonal of this wave) ----
        if ((kt + 1) * 64 > qm0) {
#pragma unroll
            for (int mi = 0; mi < 2; ++mi)
#pragma unroll
                for (int ni = 0; ni < 4; ++ni)
#pragma unroll
                    for (int j = 0; j < 4; ++j) {
                        int t   = qm0 + mi * 16 + quad * 4 + j;
                        int key = key0 + ni * 16 + l15;
                        if (key > t) s[mi][ni][j] = -1e30f;
                    }
        }
        // ---- online softmax + P (bf16, swizzled LDS) ----
#pragma unroll
        for (int mi = 0; mi < 2; ++mi) {
            f32x4 mnew;
#pragma unroll
            for (int j = 0; j < 4; ++j) {
                float mx = fmaxf(fmaxf(s[mi][0][j], s[mi][1][j]), fmaxf(s[mi][2][j], s[mi][3][j]));
                mx = fmaxf(mx, __shfl_xor(mx, 1));
                mx = fmaxf(mx, __shfl_xor(mx, 2));
                mx = fmaxf(mx, __shfl_xor(mx, 4));
                mx = fmaxf(mx, __shfl_xor(mx, 8));
                mnew[j] = fmaxf(m_r[mi][j], mx);
            }
            f32x4 alpha;
#pragma unroll
            for (int j = 0; j < 4; ++j)
                alpha[j] = __builtin_amdgcn_exp2f(m_r[mi][j] - mnew[j]);
            m_r[mi] = mnew;
            f32x4 rs = (f32x4){0.f, 0.f, 0.f, 0.f};
#pragma unroll
            for (int ni = 0; ni < 4; ++ni)
#pragma unroll
                for (int j = 0; j < 4; ++j) {
                    float p = __builtin_amdgcn_exp2f(s[mi][ni][j] - mnew[j]);
                    rs[j] += p;
                    int row = mi * 16 + quad * 4 + j;
                    int col = ni * 16 + l15;
                    P[wave * 2048 + row * 64 + ((col >> 3) ^ (row & 7)) * 8 + (col & 7)] = f2bf(p);
                }
#pragma unroll
            for (int j = 0; j < 4; ++j) {
                float t = rs[j];
                t += __shfl_xor(t, 1);
                t += __shfl_xor(t, 2);
                t += __shfl_xor(t, 4);
                t += __shfl_xor(t, 8);
                rs[j] = t;
            }
            l_r[mi] = alpha * l_r[mi] + rs;
#pragma unroll
            for (int hi = 0; hi < 8; ++hi) o[mi][hi] *= alpha;
        }
        __syncthreads();                       // (b) Vs landed (K-prefetch also drains here)
        // ---- O += P V ----
#pragma unroll
        for (int sk = 0; sk < 2; ++sk) {
            short8 pa[2];
#pragma unroll
            for (int mi = 0; mi < 2; ++mi) {
                int row = mi * 16 + l15;
                pa[mi] = *(const short8*)&P[wave * 2048 + row * 64 + ((sk * 4 + quad) ^ (l15 & 7)) * 8];
            }
#pragma unroll
            for (int hi = 0; hi < 8; ++hi) {
                int row = hi * 16 + l15;
                short8 vb = *(const short8*)&Vs[sk * 4096 + row * 32 + (quad ^ (l15 & 3)) * 8];
                o[0][hi] = __builtin_amdgcn_mfma_f32_16x16x32_bf16(pa[0], vb, o[0][hi], 0, 0, 0);
                o[1][hi] = __builtin_amdgcn_mfma_f32_16x16x32_bf16(pa[1], vb, o[1][hi], 0, 0, 0);
            }
        }
        cur ^= 1;
    }

    // ---- epilogue: O / l ----
#pragma unroll
    for (int mi = 0; mi < 2; ++mi) {
        f32x4 inv;
#pragma unroll
        for (int j = 0; j < 4; ++j) inv[j] = 1.0f / l_r[mi][j];
#pragma unroll
        for (int hi = 0; hi < 8; ++hi)
#pragma unroll
            for (int j = 0; j < 4; ++j)
                out[(qbase + qm0 + mi * 16 + quad * 4 + j) * HD + hi * 16 + l15] =
                    o[mi][hi][j] * inv[j];
    }
#undef STAGE_K
#undef STAGE_V
}

// ---------------------------------------------------------------------------
extern "C" void kernel_launch(void* const* d_in, const int* in_sizes, int n_in,
                              void* d_out, int out_size, void* d_ws, size_t ws_size,
                              hipStream_t stream) {
    const float* x  = (const float*)d_in[0];
    const float* Wq = (const float*)d_in[1];
    const float* bq = (const float*)d_in[2];
    const float* Wk = (const float*)d_in[3];
    const float* bk = (const float*)d_in[4];
    const float* Wv = (const float*)d_in[5];
    const float* bv = (const float*)d_in[6];
    float* out = (float*)d_out;

    unsigned short* wt    = (unsigned short*)d_ws;                   // 786432 B
    float*          biasc = (float*)((char*)d_ws + 786432);          // 1536 B
    unsigned short* qb    = (unsigned short*)((char*)d_ws + 787968); // 8.4 MB each
    unsigned short* kb    = qb + (size_t)BATCH * SEQ * HD;
    unsigned short* vtb   = kb + (size_t)BATCH * SEQ * HD;

    prep_kernel<<<dim3(24), 256, 0, stream>>>(Wq, bq, Wk, bk, Wv, bv, wt, biasc);
    gemm_qkv<<<dim3(512), 256, 0, stream>>>(x, wt, biasc, qb, kb, vtb);
    attn_kernel<<<dim3(256), 256, 0, stream>>>(qb, kb, vtb, out);
}

// Round 4
// 319.875 us; speedup vs baseline: 1.3126x; 1.3126x over previous
//
#include <hip/hip_runtime.h>
#include <hip/hip_bf16.h>
#include <stdint.h>

#define BATCH 8
#define SEQ   4096
#define EMB   1024
#define HD    128
#define NROWS 32768

typedef __attribute__((ext_vector_type(8))) short short8;
typedef __attribute__((ext_vector_type(4))) float f32x4;

__device__ inline unsigned short f2bf(float f) {
    union { float f; unsigned int u; } c; c.f = f;
    unsigned int u = c.u;
    unsigned int r = (u + 0x7fffu + ((u >> 16) & 1u)) >> 16;
    return (unsigned short)r;
}
__device__ inline float bf2f(unsigned short u) {
    union { unsigned int i; float f; } c; c.i = ((unsigned int)u) << 16; return c.f;
}
__device__ inline unsigned int pkbf(float a, float b) {
    __hip_bfloat162 h = __float22bfloat162_rn(make_float2(a, b));
    union { __hip_bfloat162 h; unsigned int u; } c; c.h = h; return c.u;
}

#define GLDS16(gp, lp) __builtin_amdgcn_global_load_lds( \
    (const __attribute__((address_space(1))) void*)(gp), \
    (__attribute__((address_space(3))) void*)(lp), 16, 0, 0)

// ---------------------------------------------------------------------------
// prep: wt[n][k] = bf16(W[k][h]) for n = sel*128+h. 384 blocks, one row each.
// Reads hit L2 after first touch (W total 1.5 MB). Stores fully coalesced.
// ---------------------------------------------------------------------------
__global__ __launch_bounds__(256) void prep_kernel(
    const float* __restrict__ Wq, const float* __restrict__ bq,
    const float* __restrict__ Wk, const float* __restrict__ bk,
    const float* __restrict__ Wv, const float* __restrict__ bv,
    unsigned short* __restrict__ wt, float* __restrict__ biasc)
{
    const int n = blockIdx.x;           // 0..383
    const int sel = n >> 7, h = n & 127;
    const float* W = (sel == 0) ? Wq : (sel == 1) ? Wk : Wv;
    const int tid = threadIdx.x;
    const int k0 = tid * 4;
    union { unsigned short us[4]; uint2 v; } pk;
#pragma unroll
    for (int u = 0; u < 4; ++u) pk.us[u] = f2bf(W[(size_t)(k0 + u) * HD + h]);
    *(uint2*)&wt[(size_t)n * EMB + k0] = pk.v;
    if (tid == 0) {
        const float* bp = (sel == 0) ? bq : (sel == 1) ? bk : bv;
        biasc[n] = bp[h];
    }
}

// ---------------------------------------------------------------------------
// gemm_qkv: fused QKV. 512 blocks x 64 rows x all 384 cols; 8 waves, wave
// tile = 48 cols x 64 rows. Dbuf LDS, x-load issued before B-DMA so the
// ds_write waits only vmcnt(3). MFMA(A=W,B=x) -> D[wcol][xrow] for packed
// q/k stores. q pre-scaled by (1/sqrt(128))*log2e.
// ---------------------------------------------------------------------------
__global__ __launch_bounds__(512, 4) void gemm_qkv(
    const float* __restrict__ x, const unsigned short* __restrict__ wt,
    const float* __restrict__ biasc,
    unsigned short* __restrict__ q, unsigned short* __restrict__ kOut,
    unsigned short* __restrict__ vt)
{
    const int m0  = blockIdx.x * 64;
    const int tid = threadIdx.x;
    const int wave = tid >> 6, lane = tid & 63;
    const int quad = lane >> 4, l15 = lane & 15;

    __shared__ __align__(16) unsigned short As[2][64][40];   // +8 pad
    __shared__ __align__(16) unsigned short Bs[2][12288];    // [384][32] swizzled

    f32x4 acc[3][4];
#pragma unroll
    for (int i = 0; i < 3; ++i)
#pragma unroll
        for (int j = 0; j < 4; ++j) acc[i][j] = (f32x4){0.f, 0.f, 0.f, 0.f};

    const int arow = tid >> 3, akc = (tid & 7) * 4;
    float4 aR;

#define LOAD_A(kt) aR = *(const float4*)(x + (size_t)(m0 + arow) * EMB + (kt) * 32 + akc);
#define WRITE_A(buf)                                                        \
    {                                                                       \
        union { unsigned short us[4]; uint2 v; } pw;                        \
        pw.us[0] = f2bf(aR.x); pw.us[1] = f2bf(aR.y);                       \
        pw.us[2] = f2bf(aR.z); pw.us[3] = f2bf(aR.w);                       \
        *(uint2*)&As[buf][arow][akc] = pw.v;                                \
    }
#define STAGE_B(kt, buf)                                                    \
    {                                                                       \
        _Pragma("unroll")                                                   \
        for (int g = 0; g < 3; ++g) {                                       \
            int s0 = (g * 8 + wave) * 64;                                   \
            int s  = s0 + lane;                                             \
            int n  = s >> 2, c = (s & 3) ^ (n & 3);                         \
            GLDS16(wt + (size_t)n * EMB + (kt) * 32 + c * 8,                \
                   &Bs[buf][s0 * 8]);                                       \
        }                                                                   \
    }

    LOAD_A(0); STAGE_B(0, 0); WRITE_A(0);
    int cur = 0;

    for (int kt = 0; kt < 32; ++kt) {
        __syncthreads();
        if (kt < 31) { LOAD_A(kt + 1); STAGE_B(kt + 1, cur ^ 1); }
        short8 af[4], bw[3];
#pragma unroll
        for (int mj = 0; mj < 4; ++mj)
            af[mj] = *(const short8*)&As[cur][mj * 16 + l15][quad * 8];
#pragma unroll
        for (int ni = 0; ni < 3; ++ni) {
            int n = wave * 48 + ni * 16 + l15;
            bw[ni] = *(const short8*)&Bs[cur][n * 32 + ((quad ^ (n & 3)) << 3)];
        }
#pragma unroll
        for (int ni = 0; ni < 3; ++ni)
#pragma unroll
            for (int mj = 0; mj < 4; ++mj)
                acc[ni][mj] = __builtin_amdgcn_mfma_f32_16x16x32_bf16(
                    bw[ni], af[mj], acc[ni][mj], 0, 0, 0);
        if (kt < 31) WRITE_A(cur ^ 1);
        cur ^= 1;
    }

    const float qscale = 0.08838834764831845f * 1.4426950408889634f;
    const int bb = m0 >> 12;
    const int t0 = m0 & 4095;
#pragma unroll
    for (int ni = 0; ni < 3; ++ni) {
        int colbase = wave * 48 + ni * 16;
        int sel = colbase >> 7;
        int c0 = colbase + quad * 4;
        float4 bv4 = *(const float4*)&biasc[c0];
#pragma unroll
        for (int mj = 0; mj < 4; ++mj) {
            int m = m0 + mj * 16 + l15;
            if (sel == 0) {
                union { unsigned short us[4]; uint2 v; } pk;
#pragma unroll
                for (int j = 0; j < 4; ++j)
                    pk.us[j] = f2bf((acc[ni][mj][j] + ((const float*)&bv4)[j]) * qscale);
                *(uint2*)&q[(size_t)m * HD + (c0 & 127)] = pk.v;
            } else if (sel == 1) {
                union { unsigned short us[4]; uint2 v; } pk;
#pragma unroll
                for (int j = 0; j < 4; ++j)
                    pk.us[j] = f2bf(acc[ni][mj][j] + ((const float*)&bv4)[j]);
                *(uint2*)&kOut[(size_t)m * HD + (c0 & 127)] = pk.v;
            } else {
#pragma unroll
                for (int j = 0; j < 4; ++j) {
                    int h = (c0 & 127) + j;
                    vt[((size_t)(bb * 128 + h)) * SEQ + t0 + mj * 16 + l15] =
                        f2bf(acc[ni][mj][j] + ((const float*)&bv4)[j]);
                }
            }
        }
    }
#undef LOAD_A
#undef WRITE_A
#undef STAGE_B
}

// ---------------------------------------------------------------------------
// attn: flash attention, S^T formulation. 256 blocks x 512 thr (8 waves).
// Waves 0-3 own Q-tile qtA (128 rows), waves 4-7 own Q-tile 31-qtA; both
// share one parity-split key loop (kt = parity+2i), dbuf K/V, 1 barrier/iter.
// S^T via mfma(K,Q): softmax is per-lane scalar + 2 shuffles; P^T built via
// ds_bpermute (no P LDS, no extra barrier); O^T via mfma(Vt, P^T) -> packed
// row-major epilogue. Halves merged by merge_kernel.
// ---------------------------------------------------------------------------
__global__ __launch_bounds__(512, 2) void attn_kernel(
    const unsigned short* __restrict__ q, const unsigned short* __restrict__ k,
    const unsigned short* __restrict__ vt, float* __restrict__ outA,
    unsigned short* __restrict__ Oh, float2* __restrict__ ml)
{
    const int rank   = blockIdx.x;            // 0..255
    const int qtA    = 31 - (rank >> 4);      // heavy pair first
    const int parity = (rank >> 3) & 1;
    const int b      = rank & 7;
    const int tid  = threadIdx.x;
    const int wave = tid >> 6, lane = tid & 63;
    const int quad = lane >> 4, l15 = lane & 15;
    const int qtW   = (wave < 4) ? qtA : (31 - qtA);
    const int qrow0 = qtW * 128 + (wave & 3) * 32;
    const size_t qbase = (size_t)b * SEQ;
    const size_t vbase = (size_t)b * HD * SEQ;

    __shared__ __align__(16) unsigned short Ks[2][8192];  // [64 key][16 ch sw]
    __shared__ __align__(16) unsigned short Vs[2][8192];  // [128 h][8 ch sw]

#define STAGE_KV(kt_, buf_)                                                  \
    {                                                                        \
        _Pragma("unroll")                                                    \
        for (int g = 0; g < 2; ++g) {                                        \
            int s0 = (g * 8 + wave) * 64;                                    \
            int s  = s0 + lane;                                              \
            int key = s >> 4, c = (s & 15) ^ (key & 15);                     \
            GLDS16(k + (qbase + (kt_) * 64 + key) * HD + c * 8,              \
                   &Ks[buf_][s0 * 8]);                                       \
        }                                                                    \
        _Pragma("unroll")                                                    \
        for (int g = 0; g < 2; ++g) {                                        \
            int s0 = (g * 8 + wave) * 64;                                    \
            int s  = s0 + lane;                                              \
            int h = s >> 3, c = (s & 7) ^ (h & 7);                           \
            GLDS16(vt + vbase + (size_t)h * SEQ + (kt_) * 64 + c * 8,        \
                   &Vs[buf_][s0 * 8]);                                       \
        }                                                                    \
    }

    // Q resident as B-operand frags
    short8 qf[2][4];
#pragma unroll
    for (int mi = 0; mi < 2; ++mi)
#pragma unroll
        for (int kh = 0; kh < 4; ++kh)
            qf[mi][kh] = *(const short8*)(q + (qbase + qrow0 + mi * 16 + l15) * HD + kh * 32 + quad * 8);

    f32x4 o[2][8];
#pragma unroll
    for (int mi = 0; mi < 2; ++mi)
#pragma unroll
        for (int hi = 0; hi < 8; ++hi) o[mi][hi] = (f32x4){0.f, 0.f, 0.f, 0.f};
    float m_r[2] = {-1e30f, -1e30f};
    float l_r[2] = {0.f, 0.f};

    const int bpa0 = (l15 + 16 * ((2 * quad) & 3)) * 4;       // bpermute byte addrs
    const int bpa1 = (l15 + 16 * ((2 * quad + 1) & 3)) * 4;

    const int niter = qtA + 1;
    STAGE_KV(parity, 0);
    int cur = 0;

    for (int i = 0; i < niter; ++i) {
        const int kt = parity + 2 * i;
        const int key0 = kt * 64;
        __syncthreads();                     // buf[cur] ready; prev reads retired
        if (i + 1 < niter) STAGE_KV(kt + 2, cur ^ 1);

        if (i <= qtW) {
            // ---- S^T = K Q^T : D[key][qrow], lane=qrow, regs=keys ----
            f32x4 s[2][4];
#pragma unroll
            for (int mi = 0; mi < 2; ++mi)
#pragma unroll
                for (int ni = 0; ni < 4; ++ni) s[mi][ni] = (f32x4){0.f, 0.f, 0.f, 0.f};
#pragma unroll
            for (int kh = 0; kh < 4; ++kh) {
#pragma unroll
                for (int ni = 0; ni < 4; ++ni) {
                    short8 kf = *(const short8*)&Ks[cur][(ni * 16 + l15) * 128 + (((kh * 4 + quad) ^ l15) << 3)];
                    s[0][ni] = __builtin_amdgcn_mfma_f32_16x16x32_bf16(kf, qf[0][kh], s[0][ni], 0, 0, 0);
                    s[1][ni] = __builtin_amdgcn_mfma_f32_16x16x32_bf16(kf, qf[1][kh], s[1][ni], 0, 0, 0);
                }
            }
            // ---- causal mask ----
            if (key0 + 63 > qrow0) {
#pragma unroll
                for (int mi = 0; mi < 2; ++mi)
#pragma unroll
                    for (int ni = 0; ni < 4; ++ni)
#pragma unroll
                        for (int j = 0; j < 4; ++j) {
                            int key = key0 + ni * 16 + quad * 4 + j;
                            int t   = qrow0 + mi * 16 + l15;
                            if (key > t) s[mi][ni][j] = -1e30f;
                        }
            }
            // ---- online softmax (scalar per lane) + P pack ----
            unsigned int pk[2][4][2];
#pragma unroll
            for (int mi = 0; mi < 2; ++mi) {
                float mx = -1e30f;
#pragma unroll
                for (int ni = 0; ni < 4; ++ni)
#pragma unroll
                    for (int j = 0; j < 4; ++j) mx = fmaxf(mx, s[mi][ni][j]);
                mx = fmaxf(mx, __shfl_xor(mx, 16));
                mx = fmaxf(mx, __shfl_xor(mx, 32));
                float mnew = fmaxf(m_r[mi], mx);
                float alpha = __builtin_amdgcn_exp2f(m_r[mi] - mnew);
                m_r[mi] = mnew;
                float rs = 0.f;
#pragma unroll
                for (int ni = 0; ni < 4; ++ni) {
                    float p0 = __builtin_amdgcn_exp2f(s[mi][ni][0] - mnew);
                    float p1 = __builtin_amdgcn_exp2f(s[mi][ni][1] - mnew);
                    float p2 = __builtin_amdgcn_exp2f(s[mi][ni][2] - mnew);
                    float p3 = __builtin_amdgcn_exp2f(s[mi][ni][3] - mnew);
                    rs += (p0 + p1) + (p2 + p3);
                    pk[mi][ni][0] = pkbf(p0, p1);
                    pk[mi][ni][1] = pkbf(p2, p3);
                }
                rs += __shfl_xor(rs, 16);
                rs += __shfl_xor(rs, 32);
                l_r[mi] = alpha * l_r[mi] + rs;
#pragma unroll
                for (int hi = 0; hi < 8; ++hi) o[mi][hi] *= alpha;
            }
            // ---- P^T B-frags via cross-quad bpermute ----
            short8 pT[2][2];
#pragma unroll
            for (int mi = 0; mi < 2; ++mi)
#pragma unroll
                for (int sk = 0; sk < 2; ++sk) {
                    union { unsigned int u[4]; short8 s8; } pt;
                    int lo = 2 * sk, hi_ = 2 * sk + 1;
                    unsigned int a0 = (unsigned)__builtin_amdgcn_ds_bpermute(bpa0, (int)pk[mi][lo][0]);
                    unsigned int b0 = (unsigned)__builtin_amdgcn_ds_bpermute(bpa0, (int)pk[mi][hi_][0]);
                    pt.u[0] = (quad < 2) ? a0 : b0;
                    unsigned int a1 = (unsigned)__builtin_amdgcn_ds_bpermute(bpa0, (int)pk[mi][lo][1]);
                    unsigned int b1 = (unsigned)__builtin_amdgcn_ds_bpermute(bpa0, (int)pk[mi][hi_][1]);
                    pt.u[1] = (quad < 2) ? a1 : b1;
                    unsigned int a2 = (unsigned)__builtin_amdgcn_ds_bpermute(bpa1, (int)pk[mi][lo][0]);
                    unsigned int b2 = (unsigned)__builtin_amdgcn_ds_bpermute(bpa1, (int)pk[mi][hi_][0]);
                    pt.u[2] = (quad < 2) ? a2 : b2;
                    unsigned int a3 = (unsigned)__builtin_amdgcn_ds_bpermute(bpa1, (int)pk[mi][lo][1]);
                    unsigned int b3 = (unsigned)__builtin_amdgcn_ds_bpermute(bpa1, (int)pk[mi][hi_][1]);
                    pt.u[3] = (quad < 2) ? a3 : b3;
                    pT[mi][sk] = pt.s8;
                }
            // ---- O^T += V^T P^T ----
#pragma unroll
            for (int sk = 0; sk < 2; ++sk)
#pragma unroll
                for (int hi = 0; hi < 8; ++hi) {
                    short8 vf = *(const short8*)&Vs[cur][(hi * 16 + l15) * 64 + (((sk * 4 + quad) ^ (l15 & 7)) << 3)];
                    o[0][hi] = __builtin_amdgcn_mfma_f32_16x16x32_bf16(vf, pT[0][sk], o[0][hi], 0, 0, 0);
                    o[1][hi] = __builtin_amdgcn_mfma_f32_16x16x32_bf16(vf, pT[1][sk], o[1][hi], 0, 0, 0);
                }
        }
        cur ^= 1;
    }

    // ---- epilogue: unnormalized halves + (m,l) ----
#pragma unroll
    for (int mi = 0; mi < 2; ++mi) {
        size_t rowg = qbase + qrow0 + mi * 16 + l15;
        if (quad == 0) ml[(size_t)parity * NROWS + rowg] = make_float2(m_r[mi], l_r[mi]);
#pragma unroll
        for (int hi = 0; hi < 8; ++hi) {
            if (parity == 0) {
                *(f32x4*)&outA[rowg * HD + hi * 16 + quad * 4] = o[mi][hi];
            } else {
                union { unsigned short us[4]; uint2 v; } pw;
#pragma unroll
                for (int j = 0; j < 4; ++j) pw.us[j] = f2bf(o[mi][hi][j]);
                *(uint2*)&Oh[rowg * HD + hi * 16 + quad * 4] = pw.v;
            }
        }
    }
#undef STAGE_KV
}

// ---------------------------------------------------------------------------
// merge: out = (w0*O0 + w1*O1) / (w0*l0 + w1*l1), w = exp2(m - max(m0,m1)).
// ---------------------------------------------------------------------------
__global__ __launch_bounds__(256) void merge_kernel(
    float* __restrict__ out, const unsigned short* __restrict__ Oh,
    const float2* __restrict__ ml)
{
    int idx = blockIdx.x * 256 + threadIdx.x;   // < NROWS*32
    int row = idx >> 5;
    int hc  = (idx & 31) << 2;
    float2 a = ml[row];
    float2 c = ml[NROWS + row];
    float M  = fmaxf(a.x, c.x);
    float w0 = __builtin_amdgcn_exp2f(a.x - M);
    float w1 = __builtin_amdgcn_exp2f(c.x - M);
    float inv = 1.0f / (w0 * a.y + w1 * c.y);
    f32x4 o0 = *(const f32x4*)&out[(size_t)row * HD + hc];
    union { unsigned short us[4]; uint2 v; } pv;
    pv.v = *(const uint2*)&Oh[(size_t)row * HD + hc];
    f32x4 r;
#pragma unroll
    for (int j = 0; j < 4; ++j)
        r[j] = (w0 * o0[j] + w1 * bf2f(pv.us[j])) * inv;
    *(f32x4*)&out[(size_t)row * HD + hc] = r;
}

// ---------------------------------------------------------------------------
extern "C" void kernel_launch(void* const* d_in, const int* in_sizes, int n_in,
                              void* d_out, int out_size, void* d_ws, size_t ws_size,
                              hipStream_t stream) {
    const float* x  = (const float*)d_in[0];
    const float* Wq = (const float*)d_in[1];
    const float* bq = (const float*)d_in[2];
    const float* Wk = (const float*)d_in[3];
    const float* bk = (const float*)d_in[4];
    const float* Wv = (const float*)d_in[5];
    const float* bv = (const float*)d_in[6];
    float* out = (float*)d_out;

    // ws: wt 768K | biasc 1.5K | qb 8.4M | kb 8.4M | vtb 8.4M | Oh 8.4M | ml 512K
    unsigned short* wt    = (unsigned short*)d_ws;
    float*          biasc = (float*)((char*)d_ws + 786432);
    unsigned short* qb    = (unsigned short*)((char*)d_ws + 787968);
    unsigned short* kb    = qb  + (size_t)NROWS * HD;
    unsigned short* vtb   = kb  + (size_t)NROWS * HD;
    unsigned short* Oh    = vtb + (size_t)NROWS * HD;
    float2*         ml    = (float2*)((char*)d_ws + 787968 + 4ull * NROWS * HD * 2);

    prep_kernel<<<dim3(384), 256, 0, stream>>>(Wq, bq, Wk, bk, Wv, bv, wt, biasc);
    gemm_qkv<<<dim3(512), 512, 0, stream>>>(x, wt, biasc, qb, kb, vtb);
    attn_kernel<<<dim3(256), 512, 0, stream>>>(qb, kb, vtb, out, Oh, ml);
    merge_kernel<<<dim3(NROWS * 32 / 256), 256, 0, stream>>>(out, Oh, ml);
}